// Round 3
// baseline (337.591 us; speedup 1.0000x reference)
//
#include <hip/hip_runtime.h>
#include <stdint.h>

// Problem shape (fixed by reference): xs [B,T,N,D] fp32, A [1,N,N] int32
#define BB 4
#define TT 32
#define NN 128
#define DD 32
#define NPB 8                        // nodes per block (8 nodes x 32 d = 256 threads)
#define NBLK (BB * TT * (NN / NPB))  // 2048 blocks
#define CAP 16                       // band list capacity (ids, guaranteed by mexp check)

// Sortable-key boundaries: f2k(-0.8), f2k(-0.3), f2k(-0.1), f2k(0.1), f2k(0.3), f2k(0.8).
// Median of ~66 N(0,1) has sd ~0.154 -> per-lane P(outside +-0.8) ~ 1e-7; band means <= 7.8.
#define KB1 0x40B33332u
#define KB2 0x41666665u
#define KB3 0x42333332u
#define KB4 0xBDCCCCCDu
#define KB5 0xBE99999Au
#define KB6 0xBF4CCCCDu

// monotone bijection float -> sortable u32 (no NaNs in input)
__device__ __forceinline__ uint32_t f2k(float f) {
    uint32_t u = __float_as_uint(f);
    return u ^ (uint32_t)(((int32_t)u >> 31) | 0x80000000u);
}
__device__ __forceinline__ float k2f(uint32_t k) {
    uint32_t u = k ^ (uint32_t)(((int32_t)(~k) >> 31) | 0x80000000u);
    return __uint_as_float(u);
}

// Build per-node compacted neighbor lists from A (+ implicit self loop).
__global__ __launch_bounds__(64) void build_adj_kernel(const int* __restrict__ A,
                                                       int* __restrict__ deg,
                                                       uint8_t* __restrict__ nbr) {
    const int n = blockIdx.x;
    const int lane = threadIdx.x;  // 0..63
    const int* arow = A + n * NN;
    uint8_t* row = nbr + n * NN;
    const int j0 = lane, j1 = lane + 64;
    const bool b0 = (arow[j0] != 0) || (j0 == n);
    const bool b1 = (arow[j1] != 0) || (j1 == n);
    const unsigned long long m0 = __ballot(b0);
    const unsigned long long m1 = __ballot(b1);
    const unsigned long long lmask = (1ULL << lane) - 1ULL;
    const int c0 = __popcll(m0);
    if (b0) row[__popcll(m0 & lmask)] = (uint8_t)j0;
    if (b1) row[c0 + __popcll(m1 & lmask)] = (uint8_t)j1;
    if (lane == 0) deg[n] = c0 + __popcll(m1);
}

__global__ __launch_bounds__(256, 6) void median_kernel(const float* __restrict__ xs,
                                                        const int* __restrict__ deg,
                                                        const uint8_t* __restrict__ nbr,
                                                        float* __restrict__ out) {
    __shared__ uint32_t skey[NN * DD];        // 16 KB: frame as sortable keys
    __shared__ uint32_t snbr_w[NPB * NN / 4]; // 1 KB: neighbor id lists (u8)
    __shared__ int sdeg[NPB];
    __shared__ uint32_t slistw[(CAP / 4) * 256];  // 4 KB: packed band ids, column-major words
                                                  // word (e>>2)*256+tid -> bank tid%32: conflict-free

    const int tid = threadIdx.x;
    const int g = blockIdx.x;
    const int ng = g % (NN / NPB);
    const int t  = (g / (NN / NPB)) % TT;
    const int b  = g / ((NN / NPB) * TT);
    const int n0 = ng * NPB;

    const int d = tid & (DD - 1);
    const int nl = tid >> 5;  // local node 0..7
    const int n = n0 + nl;
    const int pv = (t > 0) ? 1 : 0;
    const int nv = (t < TT - 1) ? 1 : 0;

    // temporal candidates (ids 128 / 129) -- global loads issued before the barrier
    uint32_t ex0 = 0, ex1 = 0;
    int ne = 0;
    if (pv) { ex0 = f2k(xs[(((size_t)(b * TT + t - 1) * NN) + n) * DD + d]); ne = 1; }
    if (nv) {
        uint32_t v = f2k(xs[(((size_t)(b * TT + t + 1) * NN) + n) * DD + d]);
        if (ne) ex1 = v; else ex0 = v;
        ++ne;
    }

    // stage current frame -> LDS keys
    const float4* src4 = (const float4*)(xs + ((size_t)(b * TT + t) * NN) * DD);
    #pragma unroll
    for (int s = 0; s < 4; ++s) {
        int i4 = tid + (s << 8);
        float4 v = src4[i4];
        uint4 w;
        w.x = f2k(v.x); w.y = f2k(v.y); w.z = f2k(v.z); w.w = f2k(v.w);
        ((uint4*)skey)[i4] = w;
    }
    snbr_w[tid] = ((const uint32_t*)(nbr + (size_t)n0 * NN))[tid];
    if (tid < NPB) sdeg[tid] = deg[n0 + tid];
    __syncthreads();

    const int dg = sdeg[nl];
    const int k = dg + pv + nv;
    const uint32_t r = (uint32_t)((k - 1) >> 1);  // lower-median rank
    const uint8_t* nb = (const uint8_t*)snbr_w + nl * NN;

    // ---- A1: count <= each of 6 boundaries ----
    uint32_t c1 = 0, c2 = 0, c3 = 0, c4 = 0, c5 = 0, c6 = 0;
    {
        int j = 0;
        for (; j + 4 <= dg; j += 4) {
            uint32_t nw = *(const uint32_t*)(nb + j);
            #pragma unroll
            for (int q = 0; q < 4; ++q) {
                uint32_t kj = skey[((nw >> (q * 8)) & 0xFFu) * DD + d];
                c1 += (kj <= KB1); c2 += (kj <= KB2); c3 += (kj <= KB3);
                c4 += (kj <= KB4); c5 += (kj <= KB5); c6 += (kj <= KB6);
            }
        }
        for (; j < dg; ++j) {
            uint32_t kj = skey[nb[j] * DD + d];
            c1 += (kj <= KB1); c2 += (kj <= KB2); c3 += (kj <= KB3);
            c4 += (kj <= KB4); c5 += (kj <= KB5); c6 += (kj <= KB6);
        }
        if (ne >= 1) {
            c1 += (ex0 <= KB1); c2 += (ex0 <= KB2); c3 += (ex0 <= KB3);
            c4 += (ex0 <= KB4); c5 += (ex0 <= KB5); c6 += (ex0 <= KB6);
        }
        if (ne == 2) {
            c1 += (ex1 <= KB1); c2 += (ex1 <= KB2); c3 += (ex1 <= KB3);
            c4 += (ex1 <= KB4); c5 += (ex1 <= KB5); c6 += (ex1 <= KB6);
        }
    }

    // ---- band select: find i with c_{i-1} <= r < c_i ----
    bool fb = (r < c1) || (r >= c6);
    uint32_t lo = 1, hi = 0, rp = 0, mexp = 0;  // (lo, hi] band, rp = rank within band
    if (!fb) {
        if (r < c2)      { lo = KB1; hi = KB2; rp = r - c1; mexp = c2 - c1; }
        else if (r < c3) { lo = KB2; hi = KB3; rp = r - c2; mexp = c3 - c2; }
        else if (r < c4) { lo = KB3; hi = KB4; rp = r - c3; mexp = c4 - c3; }
        else if (r < c5) { lo = KB4; hi = KB5; rp = r - c4; mexp = c5 - c4; }
        else             { lo = KB5; hi = KB6; rp = r - c5; mexp = c6 - c5; }
        if (mexp > CAP) { fb = true; lo = 1; hi = 0; }
    }

    // ---- A2: compact band-member IDS into packed column-major words ----
    int mc = 0;
    uint8_t* sl8 = (uint8_t*)slistw;
    {
        int j = 0;
        for (; j + 4 <= dg; j += 4) {
            uint32_t nw = *(const uint32_t*)(nb + j);
            #pragma unroll
            for (int q = 0; q < 4; ++q) {
                uint32_t id = (nw >> (q * 8)) & 0xFFu;
                uint32_t kj = skey[id * DD + d];
                if (kj > lo && kj <= hi) {
                    sl8[((mc >> 2) << 10) + (tid << 2) + (mc & 3)] = (uint8_t)id;
                    ++mc;
                }
            }
        }
        for (; j < dg; ++j) {
            uint32_t id = nb[j];
            uint32_t kj = skey[id * DD + d];
            if (kj > lo && kj <= hi) {
                sl8[((mc >> 2) << 10) + (tid << 2) + (mc & 3)] = (uint8_t)id;
                ++mc;
            }
        }
        if (ne >= 1 && ex0 > lo && ex0 <= hi) {
            sl8[((mc >> 2) << 10) + (tid << 2) + (mc & 3)] = 128; ++mc;
        }
        if (ne == 2 && ex1 > lo && ex1 <= hi) {
            sl8[((mc >> 2) << 10) + (tid << 2) + (mc & 3)] = 129; ++mc;
        }
    }

    // ---- B: single W=16 counting pass (mc <= CAP always) ----
    uint32_t ki[16], cnt[16];
    #pragma unroll
    for (int u = 0; u < 16; ++u) {
        uint32_t wu = slistw[((u >> 2) << 8) + tid];
        uint32_t id = (wu >> ((u & 3) * 8)) & 0xFFu;
        uint32_t sv = skey[(id & 0x7Fu) * DD + d];
        uint32_t ev = (id & 1u) ? ex1 : ex0;
        uint32_t v = (id < 128u) ? sv : ev;
        ki[u] = (u < mc) ? v : 0xFFFFFFFFu;
        cnt[u] = 0;
    }
    int mm = mc;  // wave max -> uniform trip count, no divergent outer loop
    #pragma unroll
    for (int off = 32; off; off >>= 1) {
        int o = __shfl_xor(mm, off);
        mm = mm > o ? mm : o;
    }
    for (int j4 = 0; (j4 << 2) < mm; ++j4) {
        uint32_t wj = slistw[(j4 << 8) + tid];
        #pragma unroll
        for (int q = 0; q < 4; ++q) {
            int j = (j4 << 2) + q;
            uint32_t id = (wj >> (q * 8)) & 0xFFu;
            uint32_t sv = skey[(id & 0x7Fu) * DD + d];
            uint32_t ev = (id & 1u) ? ex1 : ex0;
            uint32_t kv = (id < 128u) ? sv : ev;
            kv = (j < mc) ? kv : 0xFFFFFFFFu;  // masked slot never counts
            #pragma unroll
            for (int u = 0; u < 16; ++u) cnt[u] += (kv < ki[u]);
        }
    }
    uint32_t result = 0;
    bool found = fb;
    #pragma unroll
    for (int u = 0; u < 16; ++u) {
        // strict-below count == rp identifies the rank-rp element exactly (unique per value)
        if (!found && u < mc && cnt[u] == rp) { result = ki[u]; found = true; }
    }

    // ---- duplicate-median pass (exact multiset lower-median; ~never taken) ----
    if (__ballot(!found)) {
        uint32_t eq[16];
        #pragma unroll
        for (int u = 0; u < 16; ++u) eq[u] = 0;
        for (int j4 = 0; (j4 << 2) < mm; ++j4) {
            uint32_t wj = slistw[(j4 << 8) + tid];
            #pragma unroll
            for (int q = 0; q < 4; ++q) {
                int j = (j4 << 2) + q;
                uint32_t id = (wj >> (q * 8)) & 0xFFu;
                uint32_t sv = skey[(id & 0x7Fu) * DD + d];
                uint32_t ev = (id & 1u) ? ex1 : ex0;
                uint32_t kv = (id < 128u) ? sv : ev;
                kv = (j < mc) ? kv : 0xFFFFFFFFu;
                #pragma unroll
                for (int u = 0; u < 16; ++u) eq[u] += (kv == ki[u]);
            }
        }
        #pragma unroll
        for (int u = 0; u < 16; ++u) {
            if (!found && u < mc && cnt[u] <= rp && rp < cnt[u] + eq[u]) {
                result = ki[u]; found = true;
            }
        }
    }

    // ---- full fallback (median outside +-0.8 or band > CAP; ~0.2% of waves) ----
    if (__ballot(fb)) {
        bool done = !fb;
        for (int i0 = 0; __ballot(!done && i0 < k); i0 += 8) {
            uint32_t k8[8], c8[8];
            #pragma unroll
            for (int u = 0; u < 8; ++u) {
                int i = i0 + u;
                uint32_t sv = skey[nb[i & 127] * DD + d];
                uint32_t evv = ((i - dg) == 0) ? ex0 : ex1;
                uint32_t v = (i < dg) ? sv : evv;
                k8[u] = (i < k) ? v : 0xFFFFFFFFu;
                c8[u] = 0;
            }
            for (int j = 0; j < dg; ++j) {
                uint32_t kj = skey[nb[j] * DD + d];
                #pragma unroll
                for (int u = 0; u < 8; ++u) c8[u] += (kj < k8[u]);
            }
            if (ne >= 1) {
                #pragma unroll
                for (int u = 0; u < 8; ++u) c8[u] += (ex0 < k8[u]);
            }
            if (ne == 2) {
                #pragma unroll
                for (int u = 0; u < 8; ++u) c8[u] += (ex1 < k8[u]);
            }
            #pragma unroll
            for (int u = 0; u < 8; ++u) {
                if (!done && (i0 + u) < k && c8[u] == r) { result = k8[u]; done = true; }
            }
        }
        if (__ballot(!done)) {  // duplicates across rank: exact multiset selection
            for (int i0 = 0; __ballot(!done && i0 < k); i0 += 4) {
                uint32_t k4[4], lt4[4], le4[4];
                #pragma unroll
                for (int u = 0; u < 4; ++u) {
                    int i = i0 + u;
                    uint32_t sv = skey[nb[i & 127] * DD + d];
                    uint32_t evv = ((i - dg) == 0) ? ex0 : ex1;
                    uint32_t v = (i < dg) ? sv : evv;
                    k4[u] = (i < k) ? v : 0xFFFFFFFFu;
                    lt4[u] = 0; le4[u] = 0;
                }
                for (int j = 0; j < dg; ++j) {
                    uint32_t kj = skey[nb[j] * DD + d];
                    #pragma unroll
                    for (int u = 0; u < 4; ++u) { lt4[u] += (kj < k4[u]); le4[u] += (kj <= k4[u]); }
                }
                if (ne >= 1) {
                    #pragma unroll
                    for (int u = 0; u < 4; ++u) { lt4[u] += (ex0 < k4[u]); le4[u] += (ex0 <= k4[u]); }
                }
                if (ne == 2) {
                    #pragma unroll
                    for (int u = 0; u < 4; ++u) { lt4[u] += (ex1 < k4[u]); le4[u] += (ex1 <= k4[u]); }
                }
                #pragma unroll
                for (int u = 0; u < 4; ++u) {
                    if (!done && (i0 + u) < k && lt4[u] <= r && r < le4[u]) {
                        result = k4[u]; done = true;
                    }
                }
            }
        }
    }

    out[(((size_t)(b * TT + t) * NN) + n) * DD + d] = k2f(result);
}

extern "C" void kernel_launch(void* const* d_in, const int* in_sizes, int n_in,
                              void* d_out, int out_size, void* d_ws, size_t ws_size,
                              hipStream_t stream) {
    const float* xs = (const float*)d_in[0];
    const int* A = (const int*)d_in[1];
    float* out = (float*)d_out;

    // workspace layout: deg[128] int (512 B) | nbr[128][128] u8 (16 KB)
    int* deg = (int*)d_ws;
    uint8_t* nbr = (uint8_t*)d_ws + 512;

    build_adj_kernel<<<NN, 64, 0, stream>>>(A, deg, nbr);
    median_kernel<<<NBLK, 256, 0, stream>>>(xs, deg, nbr, out);
}

// Round 4
// 252.925 us; speedup vs baseline: 1.3347x; 1.3347x over previous
//
#include <hip/hip_runtime.h>
#include <stdint.h>

// Problem shape (fixed by reference): xs [B,T,N,D] fp32, A [1,N,N] int32
#define BB 4
#define TT 32
#define NN 128
#define DD 32
#define NPB 8                        // nodes per block (8 nodes x 32 d = 256 threads)
#define NBLK (BB * TT * (NN / NPB))  // 2048 blocks
#define CAP 16                       // band list capacity (ids, guaranteed by mexp check)

// Sortable-key boundaries: f2k(-0.8), f2k(-0.3), f2k(-0.1), f2k(0.1), f2k(0.3), f2k(0.8).
// Median of ~66 N(0,1) has sd ~0.154 -> per-lane P(outside +-0.8) ~ 1e-7; band means <= 7.8.
#define KB1 0x40B33332u
#define KB2 0x41666665u
#define KB3 0x42333332u
#define KB4 0xBDCCCCCDu
#define KB5 0xBE99999Au
#define KB6 0xBF4CCCCDu

// monotone bijection float -> sortable u32 (no NaNs in input)
__device__ __forceinline__ uint32_t f2k(float f) {
    uint32_t u = __float_as_uint(f);
    return u ^ (uint32_t)(((int32_t)u >> 31) | 0x80000000u);
}
__device__ __forceinline__ float k2f(uint32_t k) {
    uint32_t u = k ^ (uint32_t)(((int32_t)(~k) >> 31) | 0x80000000u);
    return __uint_as_float(u);
}

// Build per-node compacted neighbor lists from A (+ implicit self loop).
__global__ __launch_bounds__(64) void build_adj_kernel(const int* __restrict__ A,
                                                       int* __restrict__ deg,
                                                       uint8_t* __restrict__ nbr) {
    const int n = blockIdx.x;
    const int lane = threadIdx.x;  // 0..63
    const int* arow = A + n * NN;
    uint8_t* row = nbr + n * NN;
    const int j0 = lane, j1 = lane + 64;
    const bool b0 = (arow[j0] != 0) || (j0 == n);
    const bool b1 = (arow[j1] != 0) || (j1 == n);
    const unsigned long long m0 = __ballot(b0);
    const unsigned long long m1 = __ballot(b1);
    const unsigned long long lmask = (1ULL << lane) - 1ULL;
    const int c0 = __popcll(m0);
    if (b0) row[__popcll(m0 & lmask)] = (uint8_t)j0;
    if (b1) row[c0 + __popcll(m1 & lmask)] = (uint8_t)j1;
    if (lane == 0) deg[n] = c0 + __popcll(m1);
}

// NOTE: plain __launch_bounds__(256). R3's (256,6) VGPR cap forced scratch
// spills of the phase-B register arrays: FETCH 193 MB / WRITE 234 MB of pure
// spill traffic, 2x regression. 68 VGPR no-spill (R2-verified) + 21.5 KB LDS
// -> 7 waves/SIMD and 7 blocks/CU anyway.
__global__ __launch_bounds__(256) void median_kernel(const float* __restrict__ xs,
                                                     const int* __restrict__ deg,
                                                     const uint8_t* __restrict__ nbr,
                                                     float* __restrict__ out) {
    __shared__ uint32_t skey[NN * DD];        // 16 KB: frame as sortable keys
    __shared__ uint32_t snbr_w[NPB * NN / 4]; // 1 KB: neighbor id lists (u8)
    __shared__ int sdeg[NPB];
    __shared__ uint32_t slistw[(CAP / 4) * 256];  // 4 KB: packed band ids, column-major words
                                                  // word (e>>2)*256+tid -> bank tid%32: conflict-free

    const int tid = threadIdx.x;
    const int g = blockIdx.x;
    const int ng = g % (NN / NPB);
    const int t  = (g / (NN / NPB)) % TT;
    const int b  = g / ((NN / NPB) * TT);
    const int n0 = ng * NPB;

    const int d = tid & (DD - 1);
    const int nl = tid >> 5;  // local node 0..7
    const int n = n0 + nl;
    const int pv = (t > 0) ? 1 : 0;
    const int nv = (t < TT - 1) ? 1 : 0;

    // temporal candidates (ids 128 / 129) -- global loads issued before the barrier
    uint32_t ex0 = 0, ex1 = 0;
    int ne = 0;
    if (pv) { ex0 = f2k(xs[(((size_t)(b * TT + t - 1) * NN) + n) * DD + d]); ne = 1; }
    if (nv) {
        uint32_t v = f2k(xs[(((size_t)(b * TT + t + 1) * NN) + n) * DD + d]);
        if (ne) ex1 = v; else ex0 = v;
        ++ne;
    }

    // stage current frame -> LDS keys
    const float4* src4 = (const float4*)(xs + ((size_t)(b * TT + t) * NN) * DD);
    #pragma unroll
    for (int s = 0; s < 4; ++s) {
        int i4 = tid + (s << 8);
        float4 v = src4[i4];
        uint4 w;
        w.x = f2k(v.x); w.y = f2k(v.y); w.z = f2k(v.z); w.w = f2k(v.w);
        ((uint4*)skey)[i4] = w;
    }
    snbr_w[tid] = ((const uint32_t*)(nbr + (size_t)n0 * NN))[tid];
    if (tid < NPB) sdeg[tid] = deg[n0 + tid];
    __syncthreads();

    const int dg = sdeg[nl];
    const int k = dg + pv + nv;
    const uint32_t r = (uint32_t)((k - 1) >> 1);  // lower-median rank
    const uint8_t* nb = (const uint8_t*)snbr_w + nl * NN;

    // ---- A1: count <= each of 6 boundaries ----
    uint32_t c1 = 0, c2 = 0, c3 = 0, c4 = 0, c5 = 0, c6 = 0;
    {
        int j = 0;
        for (; j + 4 <= dg; j += 4) {
            uint32_t nw = *(const uint32_t*)(nb + j);
            #pragma unroll
            for (int q = 0; q < 4; ++q) {
                uint32_t kj = skey[((nw >> (q * 8)) & 0xFFu) * DD + d];
                c1 += (kj <= KB1); c2 += (kj <= KB2); c3 += (kj <= KB3);
                c4 += (kj <= KB4); c5 += (kj <= KB5); c6 += (kj <= KB6);
            }
        }
        for (; j < dg; ++j) {
            uint32_t kj = skey[nb[j] * DD + d];
            c1 += (kj <= KB1); c2 += (kj <= KB2); c3 += (kj <= KB3);
            c4 += (kj <= KB4); c5 += (kj <= KB5); c6 += (kj <= KB6);
        }
        if (ne >= 1) {
            c1 += (ex0 <= KB1); c2 += (ex0 <= KB2); c3 += (ex0 <= KB3);
            c4 += (ex0 <= KB4); c5 += (ex0 <= KB5); c6 += (ex0 <= KB6);
        }
        if (ne == 2) {
            c1 += (ex1 <= KB1); c2 += (ex1 <= KB2); c3 += (ex1 <= KB3);
            c4 += (ex1 <= KB4); c5 += (ex1 <= KB5); c6 += (ex1 <= KB6);
        }
    }

    // ---- band select: find i with c_{i-1} <= r < c_i ----
    bool fb = (r < c1) || (r >= c6);
    uint32_t lo = 1, hi = 0, rp = 0, mexp = 0;  // (lo, hi] band, rp = rank within band
    if (!fb) {
        if (r < c2)      { lo = KB1; hi = KB2; rp = r - c1; mexp = c2 - c1; }
        else if (r < c3) { lo = KB2; hi = KB3; rp = r - c2; mexp = c3 - c2; }
        else if (r < c4) { lo = KB3; hi = KB4; rp = r - c3; mexp = c4 - c3; }
        else if (r < c5) { lo = KB4; hi = KB5; rp = r - c4; mexp = c5 - c4; }
        else             { lo = KB5; hi = KB6; rp = r - c5; mexp = c6 - c5; }
        if (mexp > CAP) { fb = true; lo = 1; hi = 0; }
    }

    // ---- A2: compact band-member IDS into packed column-major words ----
    int mc = 0;
    uint8_t* sl8 = (uint8_t*)slistw;
    {
        int j = 0;
        for (; j + 4 <= dg; j += 4) {
            uint32_t nw = *(const uint32_t*)(nb + j);
            #pragma unroll
            for (int q = 0; q < 4; ++q) {
                uint32_t id = (nw >> (q * 8)) & 0xFFu;
                uint32_t kj = skey[id * DD + d];
                if (kj > lo && kj <= hi) {
                    sl8[((mc >> 2) << 10) + (tid << 2) + (mc & 3)] = (uint8_t)id;
                    ++mc;
                }
            }
        }
        for (; j < dg; ++j) {
            uint32_t id = nb[j];
            uint32_t kj = skey[id * DD + d];
            if (kj > lo && kj <= hi) {
                sl8[((mc >> 2) << 10) + (tid << 2) + (mc & 3)] = (uint8_t)id;
                ++mc;
            }
        }
        if (ne >= 1 && ex0 > lo && ex0 <= hi) {
            sl8[((mc >> 2) << 10) + (tid << 2) + (mc & 3)] = 128; ++mc;
        }
        if (ne == 2 && ex1 > lo && ex1 <= hi) {
            sl8[((mc >> 2) << 10) + (tid << 2) + (mc & 3)] = 129; ++mc;
        }
    }

    // ---- B: single W=16 counting pass (mc <= CAP always) ----
    uint32_t ki[16], cnt[16];
    #pragma unroll
    for (int u = 0; u < 16; ++u) {
        uint32_t wu = slistw[((u >> 2) << 8) + tid];
        uint32_t id = (wu >> ((u & 3) * 8)) & 0xFFu;
        uint32_t sv = skey[(id & 0x7Fu) * DD + d];
        uint32_t ev = (id & 1u) ? ex1 : ex0;
        uint32_t v = (id < 128u) ? sv : ev;
        ki[u] = (u < mc) ? v : 0xFFFFFFFFu;
        cnt[u] = 0;
    }
    int mm = mc;  // wave max -> uniform trip count, no divergent outer loop
    #pragma unroll
    for (int off = 32; off; off >>= 1) {
        int o = __shfl_xor(mm, off);
        mm = mm > o ? mm : o;
    }
    for (int j4 = 0; (j4 << 2) < mm; ++j4) {
        uint32_t wj = slistw[(j4 << 8) + tid];
        #pragma unroll
        for (int q = 0; q < 4; ++q) {
            int j = (j4 << 2) + q;
            uint32_t id = (wj >> (q * 8)) & 0xFFu;
            uint32_t sv = skey[(id & 0x7Fu) * DD + d];
            uint32_t ev = (id & 1u) ? ex1 : ex0;
            uint32_t kv = (id < 128u) ? sv : ev;
            kv = (j < mc) ? kv : 0xFFFFFFFFu;  // masked slot never counts
            #pragma unroll
            for (int u = 0; u < 16; ++u) cnt[u] += (kv < ki[u]);
        }
    }
    uint32_t result = 0;
    bool found = fb;
    #pragma unroll
    for (int u = 0; u < 16; ++u) {
        // strict-below count == rp identifies the rank-rp element exactly (unique per value)
        if (!found && u < mc && cnt[u] == rp) { result = ki[u]; found = true; }
    }

    // ---- duplicate-median pass (exact multiset lower-median; ~never taken) ----
    if (__ballot(!found)) {
        uint32_t eq[16];
        #pragma unroll
        for (int u = 0; u < 16; ++u) eq[u] = 0;
        for (int j4 = 0; (j4 << 2) < mm; ++j4) {
            uint32_t wj = slistw[(j4 << 8) + tid];
            #pragma unroll
            for (int q = 0; q < 4; ++q) {
                int j = (j4 << 2) + q;
                uint32_t id = (wj >> (q * 8)) & 0xFFu;
                uint32_t sv = skey[(id & 0x7Fu) * DD + d];
                uint32_t ev = (id & 1u) ? ex1 : ex0;
                uint32_t kv = (id < 128u) ? sv : ev;
                kv = (j < mc) ? kv : 0xFFFFFFFFu;
                #pragma unroll
                for (int u = 0; u < 16; ++u) eq[u] += (kv == ki[u]);
            }
        }
        #pragma unroll
        for (int u = 0; u < 16; ++u) {
            if (!found && u < mc && cnt[u] <= rp && rp < cnt[u] + eq[u]) {
                result = ki[u]; found = true;
            }
        }
    }

    // ---- full fallback (median outside +-0.8 or band > CAP; ~0.2% of waves) ----
    if (__ballot(fb)) {
        bool done = !fb;
        for (int i0 = 0; __ballot(!done && i0 < k); i0 += 8) {
            uint32_t k8[8], c8[8];
            #pragma unroll
            for (int u = 0; u < 8; ++u) {
                int i = i0 + u;
                uint32_t sv = skey[nb[i & 127] * DD + d];
                uint32_t evv = ((i - dg) == 0) ? ex0 : ex1;
                uint32_t v = (i < dg) ? sv : evv;
                k8[u] = (i < k) ? v : 0xFFFFFFFFu;
                c8[u] = 0;
            }
            for (int j = 0; j < dg; ++j) {
                uint32_t kj = skey[nb[j] * DD + d];
                #pragma unroll
                for (int u = 0; u < 8; ++u) c8[u] += (kj < k8[u]);
            }
            if (ne >= 1) {
                #pragma unroll
                for (int u = 0; u < 8; ++u) c8[u] += (ex0 < k8[u]);
            }
            if (ne == 2) {
                #pragma unroll
                for (int u = 0; u < 8; ++u) c8[u] += (ex1 < k8[u]);
            }
            #pragma unroll
            for (int u = 0; u < 8; ++u) {
                if (!done && (i0 + u) < k && c8[u] == r) { result = k8[u]; done = true; }
            }
        }
        if (__ballot(!done)) {  // duplicates across rank: exact multiset selection
            for (int i0 = 0; __ballot(!done && i0 < k); i0 += 4) {
                uint32_t k4[4], lt4[4], le4[4];
                #pragma unroll
                for (int u = 0; u < 4; ++u) {
                    int i = i0 + u;
                    uint32_t sv = skey[nb[i & 127] * DD + d];
                    uint32_t evv = ((i - dg) == 0) ? ex0 : ex1;
                    uint32_t v = (i < dg) ? sv : evv;
                    k4[u] = (i < k) ? v : 0xFFFFFFFFu;
                    lt4[u] = 0; le4[u] = 0;
                }
                for (int j = 0; j < dg; ++j) {
                    uint32_t kj = skey[nb[j] * DD + d];
                    #pragma unroll
                    for (int u = 0; u < 4; ++u) { lt4[u] += (kj < k4[u]); le4[u] += (kj <= k4[u]); }
                }
                if (ne >= 1) {
                    #pragma unroll
                    for (int u = 0; u < 4; ++u) { lt4[u] += (ex0 < k4[u]); le4[u] += (ex0 <= k4[u]); }
                }
                if (ne == 2) {
                    #pragma unroll
                    for (int u = 0; u < 4; ++u) { lt4[u] += (ex1 < k4[u]); le4[u] += (ex1 <= k4[u]); }
                }
                #pragma unroll
                for (int u = 0; u < 4; ++u) {
                    if (!done && (i0 + u) < k && lt4[u] <= r && r < le4[u]) {
                        result = k4[u]; done = true;
                    }
                }
            }
        }
    }

    out[(((size_t)(b * TT + t) * NN) + n) * DD + d] = k2f(result);
}

extern "C" void kernel_launch(void* const* d_in, const int* in_sizes, int n_in,
                              void* d_out, int out_size, void* d_ws, size_t ws_size,
                              hipStream_t stream) {
    const float* xs = (const float*)d_in[0];
    const int* A = (const int*)d_in[1];
    float* out = (float*)d_out;

    // workspace layout: deg[128] int (512 B) | nbr[128][128] u8 (16 KB)
    int* deg = (int*)d_ws;
    uint8_t* nbr = (uint8_t*)d_ws + 512;

    build_adj_kernel<<<NN, 64, 0, stream>>>(A, deg, nbr);
    median_kernel<<<NBLK, 256, 0, stream>>>(xs, deg, nbr, out);
}

// Round 5
// 122.654 us; speedup vs baseline: 2.7524x; 2.0621x over previous
//
#include <hip/hip_runtime.h>
#include <stdint.h>
#include <math.h>

// Problem shape (fixed by reference): xs [B,T,N,D] fp32, A [1,N,N] int32
#define BB 4
#define TT 32
#define NN 128
#define DD 32
#define NPB 8                        // nodes per block (8 nodes x 32 d = 256 threads)
#define NBLK (BB * TT * (NN / NPB))  // 2048 blocks
#define CAP 16                       // band list capacity (floats); selected-bin overflow -> exact fallback

// Arithmetic 8-bin partition of the value axis. ANY monotone non-decreasing
// bin function gives exact rank selection (equal values -> equal bins, so
// bins partition the multiset in value order). Bins ~[-0.8+0.2b, -0.6+0.2b),
// ends open via clamp. Median of ~66 N(0,1) lands in interior bins with
// count <= CAP except ~1e-5/lane -> fallback is exact anyway.
__device__ __forceinline__ int bin8(float x) {
    int i = (int)fmaf(x, 5.0f, 4.0f);   // trunc; monotone non-decreasing
    i = i < 0 ? 0 : i;
    return i > 7 ? 7 : i;
}

// Build per-node compacted neighbor lists from A (+ implicit self loop).
__global__ __launch_bounds__(64) void build_adj_kernel(const int* __restrict__ A,
                                                       int* __restrict__ deg,
                                                       uint8_t* __restrict__ nbr) {
    const int n = blockIdx.x;
    const int lane = threadIdx.x;  // 0..63
    const int* arow = A + n * NN;
    uint8_t* row = nbr + n * NN;
    const int j0 = lane, j1 = lane + 64;
    const bool b0 = (arow[j0] != 0) || (j0 == n);
    const bool b1 = (arow[j1] != 0) || (j1 == n);
    const unsigned long long m0 = __ballot(b0);
    const unsigned long long m1 = __ballot(b1);
    const unsigned long long lmask = (1ULL << lane) - 1ULL;
    const int c0 = __popcll(m0);
    if (b0) row[__popcll(m0 & lmask)] = (uint8_t)j0;
    if (b1) row[c0 + __popcll(m1 & lmask)] = (uint8_t)j1;
    if (lane == 0) deg[n] = c0 + __popcll(m1);
}

// Plain __launch_bounds__(256): R3 showed a waves/EU hint forces spills
// (FETCH/WRITE ~200MB scratch traffic, 2x regression). LDS (~35 KB) limits
// to 4 blocks/CU; VGPR ~72 allows 6+ waves/SIMD, so LDS is the binding cap.
__global__ __launch_bounds__(256) void median_kernel(const float* __restrict__ xs,
                                                     const int* __restrict__ deg,
                                                     const uint8_t* __restrict__ nbr,
                                                     float* __restrict__ out) {
    __shared__ float sval[NN * DD];           // 16 KB: current frame values
    __shared__ uint32_t snbr_w[NPB * NN / 4]; // 1 KB: neighbor id lists (u8)
    __shared__ int sdeg[NPB];
    __shared__ float slist[(CAP + 1) * 256];  // 17 KB: band values, column-major
                                              // slist[e*256+tid] -> bank tid%32 (2-way = free)

    const int tid = threadIdx.x;
    const int g = blockIdx.x;
    const int ng = g % (NN / NPB);
    const int t  = (g / (NN / NPB)) % TT;
    const int b  = g / ((NN / NPB) * TT);
    const int n0 = ng * NPB;

    const int d = tid & (DD - 1);
    const int nl = tid >> 5;  // local node 0..7
    const int n = n0 + nl;
    const int pv = (t > 0) ? 1 : 0;        // wave-uniform
    const int nv = (t < TT - 1) ? 1 : 0;   // wave-uniform
    const int ne = pv + nv;

    // temporal candidates as floats (coalesced; issued before the barrier)
    float exv0 = 0.0f, exv1 = 0.0f;
    if (pv) exv0 = xs[(((size_t)(b * TT + t - 1) * NN) + n) * DD + d];
    if (nv) {
        float v = xs[(((size_t)(b * TT + t + 1) * NN) + n) * DD + d];
        if (pv) exv1 = v; else exv0 = v;
    }

    // stage current frame (float4 coalesced, ds_write_b128)
    const float4* src4 = (const float4*)(xs + ((size_t)(b * TT + t) * NN) * DD);
    #pragma unroll
    for (int s = 0; s < 4; ++s) {
        int i4 = tid + (s << 8);
        ((float4*)sval)[i4] = src4[i4];
    }
    snbr_w[tid] = ((const uint32_t*)(nbr + (size_t)n0 * NN))[tid];  // exactly 256 words
    if (tid < NPB) sdeg[tid] = deg[n0 + tid];
    __syncthreads();

    const int dg = sdeg[nl];
    const int k = dg + ne;
    const uint32_t r = (uint32_t)((k - 1) >> 1);  // lower-median rank (0-based)
    const uint8_t* nb = (const uint8_t*)snbr_w + nl * NN;
    const float INFV = __uint_as_float(0x7F800000u);

    // ---- A1: one-pass 8-bin histogram, packed 8x8-bit in u64 ----
    unsigned long long pcnt = 0ull;
    {
        int j = 0;
        for (; j + 4 <= dg; j += 4) {
            uint32_t nw = *(const uint32_t*)(nb + j);
            #pragma unroll
            for (int q = 0; q < 4; ++q) {
                float x = sval[((nw >> (q * 8)) & 0xFFu) * DD + d];
                pcnt += 1ull << (bin8(x) * 8);
            }
        }
        for (; j < dg; ++j) {
            float x = sval[nb[j] * DD + d];
            pcnt += 1ull << (bin8(x) * 8);
        }
        if (ne >= 1) pcnt += 1ull << (bin8(exv0) * 8);
        if (ne == 2) pcnt += 1ull << (bin8(exv1) * 8);
    }

    // ---- prefix over 8 byte-counts; select bin containing rank r ----
    uint32_t cum = 0, lowcnt = 0, mexp = 0;
    int selbin = -1;
    #pragma unroll
    for (int bb = 0; bb < 8; ++bb) {
        uint32_t bc = (uint32_t)(pcnt >> (bb * 8)) & 0xFFu;
        uint32_t nc = cum + bc;
        if (selbin < 0 && r < nc) { selbin = bb; lowcnt = cum; mexp = bc; }
        cum = nc;
    }
    const bool fb = (mexp > CAP);          // only fallback: band too big
    const uint32_t rp = r - lowcnt;        // rank within band
    const int storebin = fb ? -1 : selbin; // fb lanes store nothing (mc stays 0)

    // ---- A2: branchless compaction of band VALUES (always-store; member's
    // write is always the last write to its slot before mc advances) ----
    int mc = 0;
    {
        int j = 0;
        for (; j + 4 <= dg; j += 4) {
            uint32_t nw = *(const uint32_t*)(nb + j);
            #pragma unroll
            for (int q = 0; q < 4; ++q) {
                float x = sval[((nw >> (q * 8)) & 0xFFu) * DD + d];
                int slot = mc > CAP ? CAP : mc;
                slist[slot * 256 + tid] = x;
                mc += (bin8(x) == storebin);
            }
        }
        for (; j < dg; ++j) {
            float x = sval[nb[j] * DD + d];
            int slot = mc > CAP ? CAP : mc;
            slist[slot * 256 + tid] = x;
            mc += (bin8(x) == storebin);
        }
        if (ne >= 1) {
            int slot = mc > CAP ? CAP : mc;
            slist[slot * 256 + tid] = exv0;
            mc += (bin8(exv0) == storebin);
        }
        if (ne == 2) {
            int slot = mc > CAP ? CAP : mc;
            slist[slot * 256 + tid] = exv1;
            mc += (bin8(exv1) == storebin);
        }
    }

    // ---- B: single W=16 counting pass over the band (mc <= CAP) ----
    float ki[CAP];
    uint32_t cn[CAP];
    #pragma unroll
    for (int u = 0; u < CAP; ++u) {
        float v = slist[u * 256 + tid];
        ki[u] = (u < mc) ? v : INFV;
        cn[u] = 0;
    }
    int mm = mc;  // wave max -> uniform trip count
    #pragma unroll
    for (int off = 32; off; off >>= 1) {
        int o = __shfl_xor(mm, off);
        mm = mm > o ? mm : o;
    }
    for (int j = 0; j < mm; ++j) {
        float x = slist[j * 256 + tid];
        x = (j < mc) ? x : INFV;  // INF < ki never true
        #pragma unroll
        for (int u = 0; u < CAP; ++u) cn[u] += (x < ki[u]);
    }
    float result = 0.0f;
    bool found = fb;
    #pragma unroll
    for (int u = 0; u < CAP; ++u) {
        // strict-below count == rp identifies rank-rp exactly (unique per value)
        if (!found && u < mc && cn[u] == rp) { result = ki[u]; found = true; }
    }

    // ---- duplicate-median pass (exact multiset lower-median; ~never runs) ----
    if (__ballot(!found)) {
        uint32_t eq[CAP];
        #pragma unroll
        for (int u = 0; u < CAP; ++u) eq[u] = 0;
        for (int j = 0; j < mm; ++j) {
            float x = slist[j * 256 + tid];
            x = (j < mc) ? x : INFV;  // INF == finite ki is false
            #pragma unroll
            for (int u = 0; u < CAP; ++u) eq[u] += (x == ki[u]);
        }
        #pragma unroll
        for (int u = 0; u < CAP; ++u) {
            if (!found && u < mc && cn[u] <= rp && rp < cn[u] + eq[u]) {
                result = ki[u]; found = true;
            }
        }
    }

    // ---- full fallback (band > CAP; ~1e-5 of lanes): exact over all k ----
    if (__ballot(fb)) {
        bool done = !fb;
        for (int i0 = 0; __ballot(!done && i0 < k); i0 += 8) {
            float k8[8]; uint32_t c8[8];
            #pragma unroll
            for (int u = 0; u < 8; ++u) {
                int i = i0 + u;
                float sv = sval[nb[i & 127] * DD + d];
                float ev = ((i - dg) == 0) ? exv0 : exv1;
                float v = (i < dg) ? sv : ev;
                k8[u] = (i < k) ? v : INFV;
                c8[u] = 0;
            }
            for (int j = 0; j < dg; ++j) {
                float xv = sval[nb[j] * DD + d];
                #pragma unroll
                for (int u = 0; u < 8; ++u) c8[u] += (xv < k8[u]);
            }
            if (ne >= 1) {
                #pragma unroll
                for (int u = 0; u < 8; ++u) c8[u] += (exv0 < k8[u]);
            }
            if (ne == 2) {
                #pragma unroll
                for (int u = 0; u < 8; ++u) c8[u] += (exv1 < k8[u]);
            }
            #pragma unroll
            for (int u = 0; u < 8; ++u) {
                if (!done && (i0 + u) < k && c8[u] == r) { result = k8[u]; done = true; }
            }
        }
        if (__ballot(!done)) {  // duplicates across rank: exact multiset selection
            for (int i0 = 0; __ballot(!done && i0 < k); i0 += 4) {
                float k4[4]; uint32_t lt4[4], le4[4];
                #pragma unroll
                for (int u = 0; u < 4; ++u) {
                    int i = i0 + u;
                    float sv = sval[nb[i & 127] * DD + d];
                    float ev = ((i - dg) == 0) ? exv0 : exv1;
                    float v = (i < dg) ? sv : ev;
                    k4[u] = (i < k) ? v : INFV;
                    lt4[u] = 0; le4[u] = 0;
                }
                for (int j = 0; j < dg; ++j) {
                    float xv = sval[nb[j] * DD + d];
                    #pragma unroll
                    for (int u = 0; u < 4; ++u) { lt4[u] += (xv < k4[u]); le4[u] += (xv <= k4[u]); }
                }
                if (ne >= 1) {
                    #pragma unroll
                    for (int u = 0; u < 4; ++u) { lt4[u] += (exv0 < k4[u]); le4[u] += (exv0 <= k4[u]); }
                }
                if (ne == 2) {
                    #pragma unroll
                    for (int u = 0; u < 4; ++u) { lt4[u] += (exv1 < k4[u]); le4[u] += (exv1 <= k4[u]); }
                }
                #pragma unroll
                for (int u = 0; u < 4; ++u) {
                    if (!done && (i0 + u) < k && lt4[u] <= r && r < le4[u]) {
                        result = k4[u]; done = true;
                    }
                }
            }
        }
    }

    out[(((size_t)(b * TT + t) * NN) + n) * DD + d] = result;
}

extern "C" void kernel_launch(void* const* d_in, const int* in_sizes, int n_in,
                              void* d_out, int out_size, void* d_ws, size_t ws_size,
                              hipStream_t stream) {
    const float* xs = (const float*)d_in[0];
    const int* A = (const int*)d_in[1];
    float* out = (float*)d_out;

    // workspace layout: deg[128] int (512 B) | nbr[128][128] u8 (16 KB)
    int* deg = (int*)d_ws;
    uint8_t* nbr = (uint8_t*)d_ws + 512;

    build_adj_kernel<<<NN, 64, 0, stream>>>(A, deg, nbr);
    median_kernel<<<NBLK, 256, 0, stream>>>(xs, deg, nbr, out);
}